// Round 1
// baseline (46.082 us; speedup 1.0000x reference)
//
#include <hip/hip_runtime.h>

// KAT group rational activation, elementwise:
//   out = p(z) / q(z)
//   p(z) = a0 + a1 z + ... + a5 z^5          (a shared across all groups)
//   q(z) = 1 + |b1| z + |b2| z^2 + |b3| z^3 + |b4| z^4   (b per group)
// Shapes: x (4, 4096, 2048) f32, G=8 groups of 256 channels.
// Memory-bound: 268 MB traffic -> ~43 us at 6.3 TB/s.

#define D_DIM   2048
#define GROUPS  8
#define DPG     256   // channels per group

__global__ __launch_bounds__(256) void kat_rational_kernel(
    const float4* __restrict__ x4,
    const float*  __restrict__ wn,   // 6 numerator coeffs (shared)
    const float*  __restrict__ wd,   // 8*4 denominator coeffs
    float4*       __restrict__ out4,
    int n4)
{
    const int tid    = blockIdx.x * blockDim.x + threadIdx.x;
    const int stride = gridDim.x * blockDim.x;

    // Element index of this thread's first float4 is tid*4.
    // d = elem % 2048, g = d / 256  ->  g = (tid*4 >> 8) & 7 = (tid >> 6) & 7.
    // Grid stride in elements = stride*4 = 2048*256*4, a multiple of D=2048
    // (guaranteed by kernel_launch's grid choice), so g is loop-invariant.
    const int g = (tid >> 6) & (GROUPS - 1);

    const float a0 = wn[0], a1 = wn[1], a2 = wn[2];
    const float a3 = wn[3], a4 = wn[4], a5 = wn[5];
    const float c1 = fabsf(wd[g * 4 + 0]);
    const float c2 = fabsf(wd[g * 4 + 1]);
    const float c3 = fabsf(wd[g * 4 + 2]);
    const float c4 = fabsf(wd[g * 4 + 3]);

    for (int i = tid; i < n4; i += stride) {
        float4 v = x4[i];
        float r[4];
        float zs[4] = {v.x, v.y, v.z, v.w};
#pragma unroll
        for (int j = 0; j < 4; ++j) {
            const float z = zs[j];
            float p = fmaf(a5, z, a4);
            p = fmaf(p, z, a3);
            p = fmaf(p, z, a2);
            p = fmaf(p, z, a1);
            p = fmaf(p, z, a0);
            float q = fmaf(c4, z, c3);
            q = fmaf(q, z, c2);
            q = fmaf(q, z, c1);
            q = fmaf(q, z, 1.0f);
            r[j] = p / q;   // IEEE f32 division (no fast-math) for accuracy
        }
        float4 o;
        o.x = r[0]; o.y = r[1]; o.z = r[2]; o.w = r[3];
        out4[i] = o;
    }
}

extern "C" void kernel_launch(void* const* d_in, const int* in_sizes, int n_in,
                              void* d_out, int out_size, void* d_ws, size_t ws_size,
                              hipStream_t stream) {
    const float* x  = (const float*)d_in[0];
    const float* wn = (const float*)d_in[1];  // (1,6) numerator
    const float* wd = (const float*)d_in[2];  // (8,4) denominator
    float* out = (float*)d_out;

    const int n  = in_sizes[0];       // 33,554,432
    const int n4 = n / 4;             // 8,388,608 float4s

    // 2048 blocks x 256 threads = 8 blocks/CU on 256 CUs, full occupancy.
    // stride*4 elements = 2,097,152 = multiple of D=2048 -> group index
    // is loop-invariant per thread (required by the kernel's hoisting).
    const int block = 256;
    const int grid  = 2048;
    kat_rational_kernel<<<grid, block, 0, stream>>>(
        (const float4*)x, wn, wd, (float4*)out, n4);
}